// Round 2
// baseline (278.376 us; speedup 1.0000x reference)
//
#include <hip/hip_runtime.h>
#include <math.h>

// ---------------------------------------------------------------------------
// SpatialProximityHead on MI355X — round 1: latency-hiding rework.
// attn: 512 thr/block, t=key scores, broadcast-q, float4 PV + 4-way k-split.
// gemm: 32x32 tiles, 256 thr, K-split-2 -> 128 blocks/problem.
// ---------------------------------------------------------------------------

#define NTOK 512
#define HDIM 256
#define DKH  64
#define NHEAD 4
#define TLEN 6
#define PSP 516   // padded ps stride

struct GArg { const float* A; const float* W; const float* b; float* C; };

// ---------------------------------------------------------------------------
__global__ __launch_bounds__(256) void dist_rows(const float* __restrict__ pl,
                                                 float* __restrict__ dist,
                                                 float* __restrict__ dwraw)
{
    const int n = blockIdx.x;
    const int t = threadIdx.x;
    const float qex = pl[n * 33 + 30];
    const float qey = pl[n * 33 + 31];
    const float qez = pl[n * 33 + 32];
#pragma unroll
    for (int c = 0; c < 2; ++c) {
        const int m = t + c * 256;
        const float dx = pl[m * 33 + 0] - qex;
        const float dy = pl[m * 33 + 1] - qey;
        const float dz = pl[m * 33 + 2] - qez;
        const float dd = sqrtf(dx * dx + dy * dy + dz * dz);
        dist[n * NTOK + m]  = dd;
        dwraw[n * NTOK + m] = 1.0f / (dd + 0.01f);
    }
}

// inv_cs[m] = 1/sum_n dwraw[n][m]; block covers 32 cols, n split 8 ways.
__global__ __launch_bounds__(256) void colsum_kernel(const float* __restrict__ dwraw,
                                                     float* __restrict__ inv_cs)
{
    __shared__ float red[8][32];
    const int t  = threadIdx.x;
    const int m  = blockIdx.x * 32 + (t & 31);
    const int ng = t >> 5;
    float s = 0.f;
    for (int n = ng * 64; n < ng * 64 + 64; ++n) s += dwraw[n * NTOK + m];
    red[ng][t & 31] = s;
    __syncthreads();
    if (t < 32) {
        float a = 0.f;
#pragma unroll
        for (int g = 0; g < 8; ++g) a += red[g][t];
        inv_cs[blockIdx.x * 32 + t] = 1.0f / a;
    }
}

// ---------------------------------------------------------------------------
// GEMM: C = A(512x256) @ W(256x256) + b, optional relu. 32x32 tile,
// 256 threads, thread-halves split K (128 each), combine via LDS.
// grid (8, 16, z) = 128 blocks per problem.
// ---------------------------------------------------------------------------
__global__ __launch_bounds__(256) void gemm32(GArg g0, GArg g1, GArg g2, int relu)
{
    const GArg ga = (blockIdx.z == 0) ? g0 : (blockIdx.z == 1) ? g1 : g2;
    const int t    = threadIdx.x;
    const int half = t >> 7;
    const int tt   = t & 127;
    const int tx   = tt & 7, ty = tt >> 3;   // cols tx*4.., rows ty*2..

    __shared__ __align__(16) float Ast[2][32][36];  // [half][k][row]
    __shared__ __align__(16) float Wst[2][32][36];  // [half][k][col]
    __shared__ __align__(16) float exch[32][32];

    const int row0 = blockIdx.y * 32;
    const int col0 = blockIdx.x * 32;

    float acc[2][4] = {};

    for (int kt = 0; kt < 4; ++kt) {
        const int k0 = half * 128 + kt * 32;
#pragma unroll
        for (int j = 0; j < 2; ++j) {
            const int i  = tt * 2 + j;           // 0..255
            const int r  = i >> 3, c4 = i & 7;
            const float4 av = *(const float4*)&ga.A[(row0 + r) * HDIM + k0 + c4 * 4];
            Ast[half][c4 * 4 + 0][r] = av.x;
            Ast[half][c4 * 4 + 1][r] = av.y;
            Ast[half][c4 * 4 + 2][r] = av.z;
            Ast[half][c4 * 4 + 3][r] = av.w;
            *(float4*)&Wst[half][r][c4 * 4] =
                *(const float4*)&ga.W[(k0 + r) * HDIM + col0 + c4 * 4];
        }
        __syncthreads();
#pragma unroll
        for (int kk = 0; kk < 32; ++kk) {
            const float2 a = *(const float2*)&Ast[half][kk][ty * 2];
            const float4 w = *(const float4*)&Wst[half][kk][tx * 4];
            acc[0][0] += a.x * w.x; acc[0][1] += a.x * w.y;
            acc[0][2] += a.x * w.z; acc[0][3] += a.x * w.w;
            acc[1][0] += a.y * w.x; acc[1][1] += a.y * w.y;
            acc[1][2] += a.y * w.z; acc[1][3] += a.y * w.w;
        }
        __syncthreads();
    }

    if (half == 1) {
#pragma unroll
        for (int ii = 0; ii < 2; ++ii) {
            float4 o; o.x = acc[ii][0]; o.y = acc[ii][1];
            o.z = acc[ii][2]; o.w = acc[ii][3];
            *(float4*)&exch[ty * 2 + ii][tx * 4] = o;
        }
    }
    __syncthreads();
    if (half == 0) {
        float bb[4];
#pragma unroll
        for (int jj = 0; jj < 4; ++jj)
            bb[jj] = ga.b ? ga.b[col0 + tx * 4 + jj] : 0.f;
#pragma unroll
        for (int ii = 0; ii < 2; ++ii) {
            const float4 other = *(const float4*)&exch[ty * 2 + ii][tx * 4];
            float4 o;
            o.x = acc[ii][0] + other.x + bb[0];
            o.y = acc[ii][1] + other.y + bb[1];
            o.z = acc[ii][2] + other.z + bb[2];
            o.w = acc[ii][3] + other.w + bb[3];
            if (relu) {
                o.x = fmaxf(o.x, 0.f); o.y = fmaxf(o.y, 0.f);
                o.z = fmaxf(o.z, 0.f); o.w = fmaxf(o.w, 0.f);
            }
            *(float4*)&ga.C[(row0 + ty * 2 + ii) * HDIM + col0 + tx * 4] = o;
        }
    }
}

// ---------------------------------------------------------------------------
// Attention: block = (head h, 8-query tile). 512 threads (8 waves).
// scores: thread = key col m, q rows via LDS broadcast.
// softmax: one 64-lane wave per row. PV: 4-way key split, float4 v loads.
// ---------------------------------------------------------------------------
__global__ __launch_bounds__(512) void attn_kernel(
    const float* __restrict__ q, const float* __restrict__ k,
    const float* __restrict__ v, const float* __restrict__ dist,
    const float* __restrict__ dwraw, const float* __restrict__ inv_cs,
    float* __restrict__ ao)
{
    const int h  = blockIdx.x;
    const int n0 = blockIdx.y * 8;
    const int t  = threadIdx.x;

    __shared__ __align__(16) float  qs[8][64];
    __shared__ __align__(16) float  ps[8][PSP];
    __shared__ __align__(16) float4 red[512];

    if (t < 128) {
        const int r = t >> 4, c4 = t & 15;
        *(float4*)&qs[r][c4 * 4] =
            *(const float4*)&q[(n0 + r) * HDIM + h * DKH + c4 * 4];
    }
    __syncthreads();

    // ---- scores: t = key index ----
    {
        const float* kr = &k[t * HDIM + h * DKH];
        float acc[8] = {0.f, 0.f, 0.f, 0.f, 0.f, 0.f, 0.f, 0.f};
#pragma unroll
        for (int c4 = 0; c4 < 16; ++c4) {
            const float4 kv = *(const float4*)&kr[c4 * 4];
#pragma unroll
            for (int r = 0; r < 8; ++r) {
                const float4 qv = *(const float4*)&qs[r][c4 * 4];  // broadcast
                acc[r] += qv.x * kv.x + qv.y * kv.y + qv.z * kv.z + qv.w * kv.w;
            }
        }
        const float ics = (h == 0) ? inv_cs[t] : 0.f;
#pragma unroll
        for (int r = 0; r < 8; ++r) {
            float bias = 0.f;
            if (h == 0)      bias = dwraw[(n0 + r) * NTOK + t] * ics;
            else if (h == 1) bias = -dist[(n0 + r) * NTOK + t];
            ps[r][t] = acc[r] * 0.125f + bias;
        }
    }
    __syncthreads();

    // ---- softmax: wave per row ----
    {
        const int r = t >> 6, lane = t & 63;
        float vals[8];
        float mx = -1e30f;
#pragma unroll
        for (int jj = 0; jj < 8; ++jj) {
            vals[jj] = ps[r][lane + jj * 64];
            mx = fmaxf(mx, vals[jj]);
        }
#pragma unroll
        for (int o = 32; o; o >>= 1) mx = fmaxf(mx, __shfl_xor(mx, o));
        float sm = 0.f;
#pragma unroll
        for (int jj = 0; jj < 8; ++jj) {
            vals[jj] = __expf(vals[jj] - mx);
            sm += vals[jj];
        }
#pragma unroll
        for (int o = 32; o; o >>= 1) sm += __shfl_xor(sm, o);
        const float inv = 1.0f / sm;
#pragma unroll
        for (int jj = 0; jj < 8; ++jj) ps[r][lane + jj * 64] = vals[jj] * inv;
    }
    __syncthreads();

    // ---- PV: d4 = t&15 (4 dims), r = (t>>4)&7, mq = t>>7 (key quarter) ----
    {
        const int d4 = t & 15, r = (t >> 4) & 7, mq = t >> 7;
        float4 o4 = {0.f, 0.f, 0.f, 0.f};
        const float* vb = &v[(mq * 128) * HDIM + h * DKH + d4 * 4];
#pragma unroll 4
        for (int j = 0; j < 128; ++j) {
            const float4 vv = *(const float4*)&vb[j * HDIM];
            const float  p  = ps[r][mq * 128 + j];   // 4-addr broadcast
            o4.x += p * vv.x; o4.y += p * vv.y;
            o4.z += p * vv.z; o4.w += p * vv.w;
        }
        red[t] = o4;
    }
    __syncthreads();
    if (t < 128) {
        const int r = t >> 4, d4 = t & 15;
        float4 a = red[t], b = red[t + 128], c = red[t + 256], d = red[t + 384];
        float4 o;
        o.x = a.x + b.x + c.x + d.x;
        o.y = a.y + b.y + c.y + d.y;
        o.z = a.z + b.z + c.z + d.z;
        o.w = a.w + b.w + c.w + d.w;
        *(float4*)&ao[(n0 + r) * HDIM + h * DKH + d4 * 4] = o;
    }
}

// ---------------------------------------------------------------------------
__global__ __launch_bounds__(256) void resid_ln(const float* __restrict__ proj,
                                                const float* __restrict__ g,
                                                const float* __restrict__ b,
                                                float* __restrict__ x)
{
    const int n = blockIdx.x, t = threadIdx.x;
    __shared__ float red[4];
    const float y = x[n * HDIM + t] + proj[n * HDIM + t];
    float s = y;
#pragma unroll
    for (int o = 32; o; o >>= 1) s += __shfl_xor(s, o);
    if ((t & 63) == 0) red[t >> 6] = s;
    __syncthreads();
    const float mean = (red[0] + red[1] + red[2] + red[3]) * (1.0f / HDIM);
    const float c = y - mean;
    float s2 = c * c;
#pragma unroll
    for (int o = 32; o; o >>= 1) s2 += __shfl_xor(s2, o);
    __syncthreads();
    if ((t & 63) == 0) red[t >> 6] = s2;
    __syncthreads();
    const float var = (red[0] + red[1] + red[2] + red[3]) * (1.0f / HDIM);
    x[n * HDIM + t] = c * rsqrtf(var + 1e-5f) * g[t] + b[t];
}

// ---------------------------------------------------------------------------
__global__ __launch_bounds__(256) void pair_cls(const float* __restrict__ U1,
                                                const float* __restrict__ U2,
                                                const float* __restrict__ W2,
                                                const float* __restrict__ b2,
                                                float* __restrict__ out)
{
    __shared__ __align__(16) float u1s[32][260];
    __shared__ __align__(16) float u2s[32][260];
    __shared__ __align__(16) float w2s[256];
    const int t  = threadIdx.x;
    const int n0 = blockIdx.y * 32, m0 = blockIdx.x * 32;

    for (int i = t; i < 32 * 64; i += 256) {
        const int r = i >> 6, c4 = i & 63;
        *(float4*)&u1s[r][c4 * 4] = *(const float4*)&U1[(n0 + r) * HDIM + c4 * 4];
        *(float4*)&u2s[r][c4 * 4] = *(const float4*)&U2[(m0 + r) * HDIM + c4 * 4];
    }
    if (t < 64) *(float4*)&w2s[t * 4] = *(const float4*)&W2[t * 4];
    __syncthreads();

    const int tx = t & 15, ty = t >> 4;
    float acc[2][2] = {};
    for (int h4 = 0; h4 < 64; ++h4) {
        const float4 a0 = *(const float4*)&u1s[ty * 2][h4 * 4];
        const float4 a1 = *(const float4*)&u1s[ty * 2 + 1][h4 * 4];
        const float4 b0 = *(const float4*)&u2s[tx * 2][h4 * 4];
        const float4 b1 = *(const float4*)&u2s[tx * 2 + 1][h4 * 4];
        const float4 w  = *(const float4*)&w2s[h4 * 4];
#define RT(A, B) fmaxf((A) + (B), 0.f)
        acc[0][0] += RT(a0.x,b0.x)*w.x + RT(a0.y,b0.y)*w.y + RT(a0.z,b0.z)*w.z + RT(a0.w,b0.w)*w.w;
        acc[0][1] += RT(a0.x,b1.x)*w.x + RT(a0.y,b1.y)*w.y + RT(a0.z,b1.z)*w.z + RT(a0.w,b1.w)*w.w;
        acc[1][0] += RT(a1.x,b0.x)*w.x + RT(a1.y,b0.y)*w.y + RT(a1.z,b0.z)*w.z + RT(a1.w,b0.w)*w.w;
        acc[1][1] += RT(a1.x,b1.x)*w.x + RT(a1.y,b1.y)*w.y + RT(a1.z,b1.z)*w.z + RT(a1.w,b1.w)*w.w;
#undef RT
    }
    const float bb = b2[0];
#pragma unroll
    for (int ii = 0; ii < 2; ++ii)
#pragma unroll
        for (int jj = 0; jj < 2; ++jj) {
            const float val = acc[ii][jj] + bb;
            const int n = n0 + ty * 2 + ii;
            const int m = m0 + tx * 2 + jj;
#pragma unroll
            for (int tl = 0; tl < TLEN; ++tl)
                out[tl * NTOK * NTOK + n * NTOK + m] = val;
        }
}

// ---------------------------------------------------------------------------
extern "C" void kernel_launch(void* const* d_in, const int* in_sizes, int n_in,
                              void* d_out, int out_size, void* d_ws, size_t ws_size,
                              hipStream_t stream)
{
    const float* hs   = (const float*)d_in[0];
    const float* qf   = hs + 5 * NTOK * HDIM;
    const float* alp  = (const float*)d_in[1];
    const float* pl   = alp + 5 * NTOK * 33;
    const float* fc_W = (const float*)d_in[2];
    const float* fc_b = (const float*)d_in[3];
    const float* Wq   = (const float*)d_in[4];
    const float* bq   = (const float*)d_in[5];
    const float* Wk   = (const float*)d_in[6];
    const float* bk   = (const float*)d_in[7];
    const float* Wv   = (const float*)d_in[8];
    const float* bv   = (const float*)d_in[9];
    const float* Wo   = (const float*)d_in[10];
    const float* bo   = (const float*)d_in[11];
    const float* lng  = (const float*)d_in[12];
    const float* lnb  = (const float*)d_in[13];
    const float* m1W  = (const float*)d_in[14];
    const float* m1b  = (const float*)d_in[15];
    const float* m2W  = (const float*)d_in[16];
    const float* m2b  = (const float*)d_in[17];
    const float* cW1  = (const float*)d_in[18];
    const float* cb1  = (const float*)d_in[19];
    const float* cW2  = (const float*)d_in[20];
    const float* cb2  = (const float*)d_in[21];
    float* out = (float*)d_out;

    const int NN  = NTOK * NTOK;
    const int NH_ = NTOK * HDIM;
    float* ws     = (float*)d_ws;
    float* dist   = ws;
    float* dwraw  = ws + NN;
    float* inv_cs = ws + 2 * NN;
    float* x      = ws + 2 * NN + 512;
    float* q      = x + NH_;
    float* k      = q + NH_;
    float* v      = k + NH_;
    float* ao     = v + NH_;
    float* tmp    = ao + NH_;

    const GArg gz = {nullptr, nullptr, nullptr, nullptr};

    dist_rows<<<NTOK, 256, 0, stream>>>(pl, dist, dwraw);
    colsum_kernel<<<16, 256, 0, stream>>>(dwraw, inv_cs);

    gemm32<<<dim3(8, 16, 1), 256, 0, stream>>>(GArg{qf, fc_W, fc_b, x}, gz, gz, 1);

    for (int L = 0; L < 2; ++L) {
        const float* wq  = Wq + L * HDIM * HDIM;
        const float* wk  = Wk + L * HDIM * HDIM;
        const float* wv  = Wv + L * HDIM * HDIM;
        const float* wo  = Wo + L * HDIM * HDIM;
        const float* bql = bq + L * HDIM;
        const float* bkl = bk + L * HDIM;
        const float* bvl = bv + L * HDIM;
        const float* bol = bo + L * HDIM;

        gemm32<<<dim3(8, 16, 3), 256, 0, stream>>>(
            GArg{x, wq, bql, q}, GArg{x, wk, bkl, k}, GArg{x, wv, bvl, v}, 0);
        attn_kernel<<<dim3(NHEAD, NTOK / 8), 512, 0, stream>>>(
            q, k, v, dist, dwraw, inv_cs, ao);
        gemm32<<<dim3(8, 16, 1), 256, 0, stream>>>(GArg{ao, wo, bol, tmp}, gz, gz, 0);
        resid_ln<<<NTOK, 256, 0, stream>>>(tmp, lng + L * HDIM, lnb + L * HDIM, x);
    }

    gemm32<<<dim3(8, 16, 2), 256, 0, stream>>>(
        GArg{x, m1W, m1b, q}, GArg{x, m2W, m2b, k}, gz, 1);
    gemm32<<<dim3(8, 16, 2), 256, 0, stream>>>(
        GArg{q, cW1, cb1, v}, GArg{k, cW1 + HDIM * HDIM, nullptr, ao}, gz, 0);

    pair_cls<<<dim3(NTOK / 32, NTOK / 32), 256, 0, stream>>>(v, ao, cW2, cb2, out);
}

// Round 3
// 128.410 us; speedup vs baseline: 2.1679x; 2.1679x over previous
//
#include <hip/hip_runtime.h>
#include <math.h>

// ---------------------------------------------------------------------------
// SpatialProximityHead on MI355X — round 2: GEMM-formulated attention.
// qkt (tiled S=qk^T+bias) -> row softmax (in-place) -> pv (K-split) -> reduce.
// ---------------------------------------------------------------------------

#define NTOK 512
#define HDIM 256
#define DKH  64
#define NHEAD 4
#define TLEN 6

struct GArg { const float* A; const float* W; const float* b; float* C; };

// ---------------------------------------------------------------------------
__global__ __launch_bounds__(256) void dist_rows(const float* __restrict__ pl,
                                                 float* __restrict__ dist,
                                                 float* __restrict__ dwraw)
{
    const int n = blockIdx.x;
    const int t = threadIdx.x;
    const float qex = pl[n * 33 + 30];
    const float qey = pl[n * 33 + 31];
    const float qez = pl[n * 33 + 32];
#pragma unroll
    for (int c = 0; c < 2; ++c) {
        const int m = t + c * 256;
        const float dx = pl[m * 33 + 0] - qex;
        const float dy = pl[m * 33 + 1] - qey;
        const float dz = pl[m * 33 + 2] - qez;
        const float dd = sqrtf(dx * dx + dy * dy + dz * dz);
        dist[n * NTOK + m]  = dd;
        dwraw[n * NTOK + m] = 1.0f / (dd + 0.01f);
    }
}

__global__ __launch_bounds__(256) void colsum_kernel(const float* __restrict__ dwraw,
                                                     float* __restrict__ inv_cs)
{
    __shared__ float red[8][32];
    const int t  = threadIdx.x;
    const int m  = blockIdx.x * 32 + (t & 31);
    const int ng = t >> 5;
    float s = 0.f;
    for (int n = ng * 64; n < ng * 64 + 64; ++n) s += dwraw[n * NTOK + m];
    red[ng][t & 31] = s;
    __syncthreads();
    if (t < 32) {
        float a = 0.f;
#pragma unroll
        for (int g = 0; g < 8; ++g) a += red[g][t];
        inv_cs[blockIdx.x * 32 + t] = 1.0f / a;
    }
}

// ---------------------------------------------------------------------------
// Dense GEMM: C = A(512x256) @ W(256x256) + b. 32x32 tile, K-split-2.
// ---------------------------------------------------------------------------
__global__ __launch_bounds__(256) void gemm32(GArg g0, GArg g1, GArg g2, int relu)
{
    const GArg ga = (blockIdx.z == 0) ? g0 : (blockIdx.z == 1) ? g1 : g2;
    const int t    = threadIdx.x;
    const int half = t >> 7;
    const int tt   = t & 127;
    const int tx   = tt & 7, ty = tt >> 3;

    __shared__ __align__(16) float Ast[2][32][36];
    __shared__ __align__(16) float Wst[2][32][36];
    __shared__ __align__(16) float exch[32][32];

    const int row0 = blockIdx.y * 32;
    const int col0 = blockIdx.x * 32;

    float acc[2][4] = {};

    for (int kt = 0; kt < 4; ++kt) {
        const int k0 = half * 128 + kt * 32;
#pragma unroll
        for (int j = 0; j < 2; ++j) {
            const int i  = tt * 2 + j;
            const int r  = i >> 3, c4 = i & 7;
            const float4 av = *(const float4*)&ga.A[(row0 + r) * HDIM + k0 + c4 * 4];
            Ast[half][c4 * 4 + 0][r] = av.x;
            Ast[half][c4 * 4 + 1][r] = av.y;
            Ast[half][c4 * 4 + 2][r] = av.z;
            Ast[half][c4 * 4 + 3][r] = av.w;
            *(float4*)&Wst[half][r][c4 * 4] =
                *(const float4*)&ga.W[(k0 + r) * HDIM + col0 + c4 * 4];
        }
        __syncthreads();
#pragma unroll
        for (int kk = 0; kk < 32; ++kk) {
            const float2 a = *(const float2*)&Ast[half][kk][ty * 2];
            const float4 w = *(const float4*)&Wst[half][kk][tx * 4];
            acc[0][0] += a.x * w.x; acc[0][1] += a.x * w.y;
            acc[0][2] += a.x * w.z; acc[0][3] += a.x * w.w;
            acc[1][0] += a.y * w.x; acc[1][1] += a.y * w.y;
            acc[1][2] += a.y * w.z; acc[1][3] += a.y * w.w;
        }
        __syncthreads();
    }

    if (half == 1) {
#pragma unroll
        for (int ii = 0; ii < 2; ++ii) {
            float4 o; o.x = acc[ii][0]; o.y = acc[ii][1];
            o.z = acc[ii][2]; o.w = acc[ii][3];
            *(float4*)&exch[ty * 2 + ii][tx * 4] = o;
        }
    }
    __syncthreads();
    if (half == 0) {
        float bb[4];
#pragma unroll
        for (int jj = 0; jj < 4; ++jj)
            bb[jj] = ga.b ? ga.b[col0 + tx * 4 + jj] : 0.f;
#pragma unroll
        for (int ii = 0; ii < 2; ++ii) {
            const float4 other = *(const float4*)&exch[ty * 2 + ii][tx * 4];
            float4 o;
            o.x = acc[ii][0] + other.x + bb[0];
            o.y = acc[ii][1] + other.y + bb[1];
            o.z = acc[ii][2] + other.z + bb[2];
            o.w = acc[ii][3] + other.w + bb[3];
            if (relu) {
                o.x = fmaxf(o.x, 0.f); o.y = fmaxf(o.y, 0.f);
                o.z = fmaxf(o.z, 0.f); o.w = fmaxf(o.w, 0.f);
            }
            *(float4*)&ga.C[(row0 + ty * 2 + ii) * HDIM + col0 + tx * 4] = o;
        }
    }
}

// ---------------------------------------------------------------------------
// S[h][n][m] = (q_n . k_m)/8 + bias(h,n,m). Tile: 32 rows x 64 cols.
// grid (8 m-tiles, 16 n-tiles, 4 heads) = 512 blocks, 256 thr, 2x4 micro.
// ---------------------------------------------------------------------------
__global__ __launch_bounds__(256) void qkt_kernel(
    const float* __restrict__ q, const float* __restrict__ k,
    const float* __restrict__ dist, const float* __restrict__ dwraw,
    const float* __restrict__ inv_cs, float* __restrict__ S)
{
    const int h  = blockIdx.z;
    const int n0 = blockIdx.y * 32;
    const int m0 = blockIdx.x * 64;
    const int t  = threadIdx.x;

    __shared__ __align__(16) float Qs[64][36];  // [d][n]
    __shared__ __align__(16) float Ks[64][68];  // [d][m]

    // stage q tile: 32 rows x 16 float4
#pragma unroll
    for (int j = 0; j < 2; ++j) {
        const int i = t + j * 256;
        const int r = i >> 4, c4 = i & 15;
        const float4 v4 = *(const float4*)&q[(n0 + r) * HDIM + h * DKH + c4 * 4];
        Qs[c4 * 4 + 0][r] = v4.x; Qs[c4 * 4 + 1][r] = v4.y;
        Qs[c4 * 4 + 2][r] = v4.z; Qs[c4 * 4 + 3][r] = v4.w;
    }
    // stage k tile: 64 rows x 16 float4
#pragma unroll
    for (int j = 0; j < 4; ++j) {
        const int i = t + j * 256;
        const int r = i >> 4, c4 = i & 15;
        const float4 v4 = *(const float4*)&k[(m0 + r) * HDIM + h * DKH + c4 * 4];
        Ks[c4 * 4 + 0][r] = v4.x; Ks[c4 * 4 + 1][r] = v4.y;
        Ks[c4 * 4 + 2][r] = v4.z; Ks[c4 * 4 + 3][r] = v4.w;
    }
    __syncthreads();

    const int tx = t & 15, ty = t >> 4;   // cols m0+tx*4.., rows n0+ty*2..
    float acc[2][4] = {};
#pragma unroll 8
    for (int kk = 0; kk < 64; ++kk) {
        const float2 a2 = *(const float2*)&Qs[kk][ty * 2];
        const float4 b4 = *(const float4*)&Ks[kk][tx * 4];
        acc[0][0] += a2.x * b4.x; acc[0][1] += a2.x * b4.y;
        acc[0][2] += a2.x * b4.z; acc[0][3] += a2.x * b4.w;
        acc[1][0] += a2.y * b4.x; acc[1][1] += a2.y * b4.y;
        acc[1][2] += a2.y * b4.z; acc[1][3] += a2.y * b4.w;
    }

    const int m = m0 + tx * 4;
#pragma unroll
    for (int ii = 0; ii < 2; ++ii) {
        const int n = n0 + ty * 2 + ii;
        float4 bias = {0.f, 0.f, 0.f, 0.f};
        if (h == 0) {
            const float4 dw = *(const float4*)&dwraw[n * NTOK + m];
            const float4 ic = *(const float4*)&inv_cs[m];
            bias.x = dw.x * ic.x; bias.y = dw.y * ic.y;
            bias.z = dw.z * ic.z; bias.w = dw.w * ic.w;
        } else if (h == 1) {
            const float4 dd = *(const float4*)&dist[n * NTOK + m];
            bias.x = -dd.x; bias.y = -dd.y; bias.z = -dd.z; bias.w = -dd.w;
        }
        float4 o;
        o.x = acc[ii][0] * 0.125f + bias.x;
        o.y = acc[ii][1] * 0.125f + bias.y;
        o.z = acc[ii][2] * 0.125f + bias.z;
        o.w = acc[ii][3] * 0.125f + bias.w;
        *(float4*)&S[(h * NTOK + n) * NTOK + m] = o;
    }
}

// ---------------------------------------------------------------------------
// In-place row softmax over S. block = (4 rows, head); wave per row.
// ---------------------------------------------------------------------------
__global__ __launch_bounds__(256) void softmax_rows(float* __restrict__ S)
{
    const int h    = blockIdx.y;
    const int n    = blockIdx.x * 4 + (threadIdx.x >> 6);
    const int lane = threadIdx.x & 63;
    float* row = S + (h * NTOK + n) * NTOK;

    float4 a = *(const float4*)&row[lane * 4];
    float4 b = *(const float4*)&row[256 + lane * 4];
    float mx = fmaxf(fmaxf(fmaxf(a.x, a.y), fmaxf(a.z, a.w)),
                     fmaxf(fmaxf(b.x, b.y), fmaxf(b.z, b.w)));
#pragma unroll
    for (int o = 32; o; o >>= 1) mx = fmaxf(mx, __shfl_xor(mx, o));
    a.x = __expf(a.x - mx); a.y = __expf(a.y - mx);
    a.z = __expf(a.z - mx); a.w = __expf(a.w - mx);
    b.x = __expf(b.x - mx); b.y = __expf(b.y - mx);
    b.z = __expf(b.z - mx); b.w = __expf(b.w - mx);
    float sm = a.x + a.y + a.z + a.w + b.x + b.y + b.z + b.w;
#pragma unroll
    for (int o = 32; o; o >>= 1) sm += __shfl_xor(sm, o);
    const float inv = 1.0f / sm;
    a.x *= inv; a.y *= inv; a.z *= inv; a.w *= inv;
    b.x *= inv; b.y *= inv; b.z *= inv; b.w *= inv;
    *(float4*)&row[lane * 4]       = a;
    *(float4*)&row[256 + lane * 4] = b;
}

// ---------------------------------------------------------------------------
// part[ks][h][n0..n0+31][0..63] = P(rows, ks-half of K) @ V. K=256 per block
// in 2 chunks of 128. grid (16 n-tiles, 4 heads, 2 ks) = 128 blocks.
// ---------------------------------------------------------------------------
__global__ __launch_bounds__(256) void pv_partial(
    const float* __restrict__ S, const float* __restrict__ v,
    float* __restrict__ part)
{
    const int n0 = blockIdx.x * 32;
    const int h  = blockIdx.y;
    const int ks = blockIdx.z;
    const int t  = threadIdx.x;

    __shared__ __align__(16) float Ps[128][36];  // [k][n]
    __shared__ __align__(16) float Vs[128][68];  // [k][d]

    const int tx = t & 15, ty = t >> 4;
    float acc[2][4] = {};

    for (int kt = 0; kt < 2; ++kt) {
        const int kb = ks * 256 + kt * 128;
        // stage P: 32 rows x 32 float4
#pragma unroll
        for (int j = 0; j < 4; ++j) {
            const int i = t + j * 256;
            const int r = i >> 5, c4 = i & 31;
            const float4 p4 = *(const float4*)&S[(h * NTOK + n0 + r) * NTOK + kb + c4 * 4];
            Ps[c4 * 4 + 0][r] = p4.x; Ps[c4 * 4 + 1][r] = p4.y;
            Ps[c4 * 4 + 2][r] = p4.z; Ps[c4 * 4 + 3][r] = p4.w;
        }
        // stage V: 128 rows x 16 float4
#pragma unroll
        for (int j = 0; j < 8; ++j) {
            const int i = t + j * 256;
            const int r = i >> 4, c4 = i & 15;
            *(float4*)&Vs[r][c4 * 4] =
                *(const float4*)&v[(kb + r) * HDIM + h * DKH + c4 * 4];
        }
        __syncthreads();
#pragma unroll 8
        for (int kk = 0; kk < 128; ++kk) {
            const float2 a2 = *(const float2*)&Ps[kk][ty * 2];
            const float4 b4 = *(const float4*)&Vs[kk][tx * 4];
            acc[0][0] += a2.x * b4.x; acc[0][1] += a2.x * b4.y;
            acc[0][2] += a2.x * b4.z; acc[0][3] += a2.x * b4.w;
            acc[1][0] += a2.y * b4.x; acc[1][1] += a2.y * b4.y;
            acc[1][2] += a2.y * b4.z; acc[1][3] += a2.y * b4.w;
        }
        __syncthreads();
    }

#pragma unroll
    for (int ii = 0; ii < 2; ++ii) {
        float4 o; o.x = acc[ii][0]; o.y = acc[ii][1];
        o.z = acc[ii][2]; o.w = acc[ii][3];
        *(float4*)&part[((ks * NHEAD + h) * NTOK + n0 + ty * 2 + ii) * DKH + tx * 4] = o;
    }
}

// ao[n][h*64+d] = sum_ks part[ks][h][n][d]
__global__ __launch_bounds__(256) void pv_reduce(const float* __restrict__ part,
                                                 float* __restrict__ ao)
{
    const int n = blockIdx.x, t = threadIdx.x;
    const int h = t >> 6, d = t & 63;
    const float a = part[((0 * NHEAD + h) * NTOK + n) * DKH + d];
    const float b = part[((1 * NHEAD + h) * NTOK + n) * DKH + d];
    ao[n * HDIM + t] = a + b;
}

// ---------------------------------------------------------------------------
__global__ __launch_bounds__(256) void resid_ln(const float* __restrict__ proj,
                                                const float* __restrict__ g,
                                                const float* __restrict__ b,
                                                float* __restrict__ x)
{
    const int n = blockIdx.x, t = threadIdx.x;
    __shared__ float red[4];
    const float y = x[n * HDIM + t] + proj[n * HDIM + t];
    float s = y;
#pragma unroll
    for (int o = 32; o; o >>= 1) s += __shfl_xor(s, o);
    if ((t & 63) == 0) red[t >> 6] = s;
    __syncthreads();
    const float mean = (red[0] + red[1] + red[2] + red[3]) * (1.0f / HDIM);
    const float c = y - mean;
    float s2 = c * c;
#pragma unroll
    for (int o = 32; o; o >>= 1) s2 += __shfl_xor(s2, o);
    __syncthreads();
    if ((t & 63) == 0) red[t >> 6] = s2;
    __syncthreads();
    const float var = (red[0] + red[1] + red[2] + red[3]) * (1.0f / HDIM);
    x[n * HDIM + t] = c * rsqrtf(var + 1e-5f) * g[t] + b[t];
}

// ---------------------------------------------------------------------------
__global__ __launch_bounds__(256) void pair_cls(const float* __restrict__ U1,
                                                const float* __restrict__ U2,
                                                const float* __restrict__ W2,
                                                const float* __restrict__ b2,
                                                float* __restrict__ out)
{
    __shared__ __align__(16) float u1s[32][260];
    __shared__ __align__(16) float u2s[32][260];
    __shared__ __align__(16) float w2s[256];
    const int t  = threadIdx.x;
    const int n0 = blockIdx.y * 32, m0 = blockIdx.x * 32;

    for (int i = t; i < 32 * 64; i += 256) {
        const int r = i >> 6, c4 = i & 63;
        *(float4*)&u1s[r][c4 * 4] = *(const float4*)&U1[(n0 + r) * HDIM + c4 * 4];
        *(float4*)&u2s[r][c4 * 4] = *(const float4*)&U2[(m0 + r) * HDIM + c4 * 4];
    }
    if (t < 64) *(float4*)&w2s[t * 4] = *(const float4*)&W2[t * 4];
    __syncthreads();

    const int tx = t & 15, ty = t >> 4;
    float acc[2][2] = {};
    for (int h4 = 0; h4 < 64; ++h4) {
        const float4 a0 = *(const float4*)&u1s[ty * 2][h4 * 4];
        const float4 a1 = *(const float4*)&u1s[ty * 2 + 1][h4 * 4];
        const float4 b0 = *(const float4*)&u2s[tx * 2][h4 * 4];
        const float4 b1 = *(const float4*)&u2s[tx * 2 + 1][h4 * 4];
        const float4 w  = *(const float4*)&w2s[h4 * 4];
#define RT(A, B) fmaxf((A) + (B), 0.f)
        acc[0][0] += RT(a0.x,b0.x)*w.x + RT(a0.y,b0.y)*w.y + RT(a0.z,b0.z)*w.z + RT(a0.w,b0.w)*w.w;
        acc[0][1] += RT(a0.x,b1.x)*w.x + RT(a0.y,b1.y)*w.y + RT(a0.z,b1.z)*w.z + RT(a0.w,b1.w)*w.w;
        acc[1][0] += RT(a1.x,b0.x)*w.x + RT(a1.y,b0.y)*w.y + RT(a1.z,b0.z)*w.z + RT(a1.w,b0.w)*w.w;
        acc[1][1] += RT(a1.x,b1.x)*w.x + RT(a1.y,b1.y)*w.y + RT(a1.z,b1.z)*w.z + RT(a1.w,b1.w)*w.w;
#undef RT
    }
    const float bb = b2[0];
#pragma unroll
    for (int ii = 0; ii < 2; ++ii)
#pragma unroll
        for (int jj = 0; jj < 2; ++jj) {
            const float val = acc[ii][jj] + bb;
            const int n = n0 + ty * 2 + ii;
            const int m = m0 + tx * 2 + jj;
#pragma unroll
            for (int tl = 0; tl < TLEN; ++tl)
                out[tl * NTOK * NTOK + n * NTOK + m] = val;
        }
}

// ---------------------------------------------------------------------------
extern "C" void kernel_launch(void* const* d_in, const int* in_sizes, int n_in,
                              void* d_out, int out_size, void* d_ws, size_t ws_size,
                              hipStream_t stream)
{
    const float* hs   = (const float*)d_in[0];
    const float* qf   = hs + 5 * NTOK * HDIM;
    const float* alp  = (const float*)d_in[1];
    const float* pl   = alp + 5 * NTOK * 33;
    const float* fc_W = (const float*)d_in[2];
    const float* fc_b = (const float*)d_in[3];
    const float* Wq   = (const float*)d_in[4];
    const float* bq   = (const float*)d_in[5];
    const float* Wk   = (const float*)d_in[6];
    const float* bk   = (const float*)d_in[7];
    const float* Wv   = (const float*)d_in[8];
    const float* bv   = (const float*)d_in[9];
    const float* Wo   = (const float*)d_in[10];
    const float* bo   = (const float*)d_in[11];
    const float* lng  = (const float*)d_in[12];
    const float* lnb  = (const float*)d_in[13];
    const float* m1W  = (const float*)d_in[14];
    const float* m1b  = (const float*)d_in[15];
    const float* m2W  = (const float*)d_in[16];
    const float* m2b  = (const float*)d_in[17];
    const float* cW1  = (const float*)d_in[18];
    const float* cb1  = (const float*)d_in[19];
    const float* cW2  = (const float*)d_in[20];
    const float* cb2  = (const float*)d_in[21];
    float* out = (float*)d_out;

    const int NN  = NTOK * NTOK;
    const int NH_ = NTOK * HDIM;
    float* ws     = (float*)d_ws;
    float* dist   = ws;                       // NN
    float* dwraw  = ws + NN;                  // NN
    float* inv_cs = ws + 2 * NN;              // 512
    float* x      = ws + 2 * NN + 512;        // NH
    float* v      = x + NH_;                  // NH
    float* ao     = v + NH_;                  // NH
    float* tmp    = ao + NH_;                 // NH
    float* q      = tmp + NH_;                // NH   (part overlays q..k)
    float* k      = q + NH_;                  // NH
    float* S      = k + NH_;                  // NHEAD*NN (4 MB)
    float* part   = q;                        // 2*NH, q/k dead when used
    // total: 2*NN + 512 + 6*NH + 4*NN floats ~= 9.0 MB

    const GArg gz = {nullptr, nullptr, nullptr, nullptr};

    dist_rows<<<NTOK, 256, 0, stream>>>(pl, dist, dwraw);
    colsum_kernel<<<16, 256, 0, stream>>>(dwraw, inv_cs);

    gemm32<<<dim3(8, 16, 1), 256, 0, stream>>>(GArg{qf, fc_W, fc_b, x}, gz, gz, 1);

    for (int L = 0; L < 2; ++L) {
        const float* wq  = Wq + L * HDIM * HDIM;
        const float* wk  = Wk + L * HDIM * HDIM;
        const float* wv  = Wv + L * HDIM * HDIM;
        const float* wo  = Wo + L * HDIM * HDIM;

        gemm32<<<dim3(8, 16, 3), 256, 0, stream>>>(
            GArg{x, wq, bq + L * HDIM, q}, GArg{x, wk, bk + L * HDIM, k},
            GArg{x, wv, bv + L * HDIM, v}, 0);
        qkt_kernel<<<dim3(8, 16, NHEAD), 256, 0, stream>>>(
            q, k, dist, dwraw, inv_cs, S);
        softmax_rows<<<dim3(NTOK / 4, NHEAD), 256, 0, stream>>>(S);
        pv_partial<<<dim3(16, NHEAD, 2), 256, 0, stream>>>(S, v, part);
        pv_reduce<<<NTOK, 256, 0, stream>>>(part, ao);
        gemm32<<<dim3(8, 16, 1), 256, 0, stream>>>(
            GArg{ao, wo, bo + L * HDIM, tmp}, gz, gz, 0);
        resid_ln<<<NTOK, 256, 0, stream>>>(tmp, lng + L * HDIM, lnb + L * HDIM, x);
    }

    gemm32<<<dim3(8, 16, 2), 256, 0, stream>>>(
        GArg{x, m1W, m1b, q}, GArg{x, m2W, m2b, k}, gz, 1);
    gemm32<<<dim3(8, 16, 2), 256, 0, stream>>>(
        GArg{q, cW1, cb1, v}, GArg{k, cW1 + HDIM * HDIM, nullptr, ao}, gz, 0);

    pair_cls<<<dim3(NTOK / 32, NTOK / 32), 256, 0, stream>>>(v, ao, cW2, cb2, out);
}